// Round 7
// baseline (283.711 us; speedup 1.0000x reference)
//
#include <hip/hip_runtime.h>
#include <hip/hip_bf16.h>

typedef unsigned short u16;
typedef unsigned int   u32;
typedef short bf16x8 __attribute__((ext_vector_type(8)));
typedef float f32x4  __attribute__((ext_vector_type(4)));

#define N_NODES  50000
#define N_EDGES  800000
#define DIM      64
#define N_GRAPHS 64
#define OUT_DIM  10
#define POOL_BLOCKS 256
#define POOL_CHUNK  ((N_NODES + POOL_BLOCKS - 1) / POOL_BLOCKS)   // 196

// bucket CSR build
#define BSHIFT 8
#define NBUCK  196
#define BCAP   5000
#define EPB    2048
#define NBLK_A ((N_EDGES + EPB - 1) / EPB)   // 391

__device__ __forceinline__ u16 f2bf(float f) {
    u32 u = __float_as_uint(f);
    u32 r = (u + 0x7fffu + ((u >> 16) & 1u)) >> 16;
    return (u16)r;
}
__device__ __forceinline__ float bf_lo(u32 u) { return __uint_as_float(u << 16); }
__device__ __forceinline__ float bf_hi(u32 u) { return __uint_as_float(u & 0xffff0000u); }

// ---------------- bucketed CSR build ----------------
__global__ __launch_bounds__(256) void bucket_scatter(const int* __restrict__ src,
                                                      const int* __restrict__ dst,
                                                      int* __restrict__ bcur,
                                                      u32* __restrict__ bscratch) {
    __shared__ int hist[NBUCK];
    __shared__ int base[NBUCK];
    int t = threadIdx.x;
    for (int i = t; i < NBUCK; i += 256) hist[i] = 0;
    __syncthreads();
    int e0 = blockIdx.x * EPB;
    u32 packed[8];
    int bb[8];
    #pragma unroll
    for (int i = 0; i < 8; ++i) {
        int e = e0 + i * 256 + t;
        if (e < N_EDGES) {
            int d = dst[e], s = src[e];
            bb[i] = d >> BSHIFT;
            packed[i] = ((u32)s << BSHIFT) | (u32)(d & ((1 << BSHIFT) - 1));
            atomicAdd(&hist[bb[i]], 1);
        } else bb[i] = -1;
    }
    __syncthreads();
    for (int i = t; i < NBUCK; i += 256)
        base[i] = (hist[i] > 0) ? atomicAdd(&bcur[i], hist[i]) : 0;
    __syncthreads();
    #pragma unroll
    for (int i = 0; i < 8; ++i) {
        if (bb[i] >= 0) {
            int pos = atomicAdd(&base[bb[i]], 1);
            bscratch[bb[i] * BCAP + pos] = packed[i];
        }
    }
}

__global__ __launch_bounds__(256) void csr_build(const u32* __restrict__ bscratch,
                                                 const int* __restrict__ bcur,
                                                 int* __restrict__ offs,
                                                 int* __restrict__ csr) {
    __shared__ int cnt[256];
    __shared__ int sc[256];
    __shared__ int cur2[256];
    __shared__ int gb[256];
    int b = blockIdx.x, t = threadIdx.x;
    int vb = (t < b) ? bcur[t] : 0;
    gb[t] = vb;
    cnt[t] = 0;
    __syncthreads();
    for (int d = 1; d < 256; d <<= 1) {
        int tmp = (t >= d) ? gb[t - d] : 0;
        __syncthreads();
        gb[t] += tmp;
        __syncthreads();
    }
    int gbase = gb[255];
    int n_b = bcur[b];
    const u32* bp = bscratch + (size_t)b * BCAP;
    for (int i = t; i < n_b; i += 256) atomicAdd(&cnt[bp[i] & 255], 1);
    __syncthreads();
    int v = cnt[t];
    sc[t] = v;
    __syncthreads();
    for (int d = 1; d < 256; d <<= 1) {
        int tmp = (t >= d) ? sc[t - d] : 0;
        __syncthreads();
        sc[t] += tmp;
        __syncthreads();
    }
    int excl = sc[t] - v;
    int node = (b << BSHIFT) + t;
    if (node < N_NODES) offs[node] = gbase + excl;
    if (b == NBUCK - 1 && t == 0) offs[N_NODES] = N_EDGES;
    cur2[t] = gbase + excl;
    __syncthreads();
    for (int i = t; i < n_b; i += 256) {
        u32 p = bp[i];
        int pos = atomicAdd(&cur2[p & 255], 1);
        csr[pos] = (int)(p >> BSHIFT);
    }
}

// ---------------- precompute ----------------

__global__ __launch_bounds__(256) void convert_x(const float* __restrict__ x,
                                                 u16* __restrict__ hb) {
    int c = blockIdx.x * 256 + threadIdx.x;
    if (c >= N_NODES * 8) return;
    const float* src = x + (size_t)c * 8;
    float4 f0 = *(const float4*)src;
    float4 f1 = *(const float4*)(src + 4);
    uint4 pk;
    pk.x = (u32)f2bf(f0.x) | ((u32)f2bf(f0.y) << 16);
    pk.y = (u32)f2bf(f0.z) | ((u32)f2bf(f0.w) << 16);
    pk.z = (u32)f2bf(f1.x) | ((u32)f2bf(f1.y) << 16);
    pk.w = (u32)f2bf(f1.z) | ((u32)f2bf(f1.w) << 16);
    *(uint4*)(hb + (size_t)c * 8) = pk;
}

// W transpose -> bf16; tail threads zero gsums and bcur (runs FIRST in stream)
__global__ __launch_bounds__(256) void prep_w(
    const float* __restrict__ Wq, const float* __restrict__ Wk,
    const float* __restrict__ Wv, const float* __restrict__ Ws,
    u16* __restrict__ Wtb, float* __restrict__ gsums, int* __restrict__ bcur) {
    int id = blockIdx.x * 256 + threadIdx.x;
    if (id < 8192) {
        int kc  = id & 7;
        int col = (id >> 3) & 63;
        int m   = (id >> 9) & 3;
        int l   = id >> 11;
        const float* W = ((m == 0) ? Wq : (m == 1) ? Wk : (m == 2) ? Wv : Ws) + l * 4096;
        u16 b[8];
        #pragma unroll
        for (int j = 0; j < 8; ++j) b[j] = f2bf(W[(kc * 8 + j) * 64 + col]);
        uint4 pk;
        pk.x = (u32)b[0] | ((u32)b[1] << 16);
        pk.y = (u32)b[2] | ((u32)b[3] << 16);
        pk.z = (u32)b[4] | ((u32)b[5] << 16);
        pk.w = (u32)b[6] | ((u32)b[7] << 16);
        *(uint4*)(Wtb + ((size_t)(l * 256 + m * 64 + col)) * 64 + kc * 8) = pk;
    } else if (id < 8192 + N_GRAPHS * DIM) {
        gsums[id - 8192] = 0.f;
    } else if (id < 8192 + N_GRAPHS * DIM + NBUCK) {
        bcur[id - 8192 - N_GRAPHS * DIM] = 0;
    }
}

// ---------------- LDS-free MFMA GEMM: q bf16, k|v interleaved bf16, s-path bf16 ----------------
__global__ __launch_bounds__(256) void gemm_mfma(
    const u16* __restrict__ hb, const u16* __restrict__ Wtb,
    const float* __restrict__ bq, const float* __restrict__ bk,
    const float* __restrict__ bv, const float* __restrict__ bs,
    u16* __restrict__ q, u16* __restrict__ kv, u16* __restrict__ sb16) {
    int t = threadIdx.x;
    int wave = t >> 6, lane = t & 63;
    int nb = blockIdx.x * 64;
    int lr = lane & 15, lg4 = lane >> 4;

    const float* bm = (wave == 0) ? bq : (wave == 1) ? bk : (wave == 2) ? bv : bs;

    f32x4 acc[4][4];
    #pragma unroll
    for (int ct = 0; ct < 4; ++ct) {
        float bval = bm[ct * 16 + lr];
        #pragma unroll
        for (int rt = 0; rt < 4; ++rt) acc[rt][ct] = (f32x4){bval, bval, bval, bval};
    }

    const u16* wb = Wtb + (size_t)wave * 64 * 64;
    #pragma unroll
    for (int s = 0; s < 2; ++s) {
        bf16x8 af[4], bfr[4];
        #pragma unroll
        for (int rt = 0; rt < 4; ++rt)
            af[rt] = *(const bf16x8*)(hb + (size_t)(nb + rt * 16 + lr) * 64 + s * 32 + lg4 * 8);
        #pragma unroll
        for (int ct = 0; ct < 4; ++ct)
            bfr[ct] = *(const bf16x8*)(wb + (size_t)(ct * 16 + lr) * 64 + s * 32 + lg4 * 8);
        #pragma unroll
        for (int rt = 0; rt < 4; ++rt)
            #pragma unroll
            for (int ct = 0; ct < 4; ++ct)
                acc[rt][ct] = __builtin_amdgcn_mfma_f32_16x16x32_bf16(
                    af[rt], bfr[ct], acc[rt][ct], 0, 0, 0);
    }

    #pragma unroll
    for (int rt = 0; rt < 4; ++rt) {
        #pragma unroll
        for (int r = 0; r < 4; ++r) {
            int row = rt * 16 + lg4 * 4 + r;
            int node = nb + row;
            if (node >= N_NODES) continue;
            if (wave == 0) {
                #pragma unroll
                for (int ct = 0; ct < 4; ++ct)
                    q[(size_t)node * 64 + ct * 16 + lr] = f2bf(acc[rt][ct][r]);
            } else if (wave == 1) {
                #pragma unroll
                for (int ct = 0; ct < 4; ++ct) {
                    int slot = (2 * ct + (lr >> 3)) * 16 + (lr & 7);
                    kv[(size_t)node * 128 + slot] = f2bf(acc[rt][ct][r]);
                }
            } else if (wave == 2) {
                #pragma unroll
                for (int ct = 0; ct < 4; ++ct) {
                    int slot = (2 * ct + (lr >> 3)) * 16 + (lr & 7) + 8;
                    kv[(size_t)node * 128 + slot] = f2bf(acc[rt][ct][r]);
                }
            } else {
                #pragma unroll
                for (int ct = 0; ct < 4; ++ct)
                    sb16[(size_t)node * 64 + ct * 16 + lr] = f2bf(acc[rt][ct][r]);
            }
        }
    }
}

// ---------------- edge attention: 2 edges per group-iteration, deferred-max ----------------
// wave per dst; 8 groups x 8 lanes; group g owns pairs {e0+2g, e0+2g+1}, stride 16.
__global__ __launch_bounds__(256) void edge_attn(
    const u16* __restrict__ q, const u16* __restrict__ kv,
    const int* __restrict__ offs, const int* __restrict__ csr_src,
    const u16* __restrict__ sb16,
    float* __restrict__ hfin, u16* __restrict__ hb, int last) {
    int wave = threadIdx.x >> 6, lane = threadIdx.x & 63;
    int n = blockIdx.x * 4 + wave;
    int g = lane >> 3, lg = lane & 7;
    uint4 qu = *(const uint4*)(q + (size_t)n * 64 + lg * 8);
    float q0 = bf_lo(qu.x), q1 = bf_hi(qu.x);
    float q2 = bf_lo(qu.y), q3 = bf_hi(qu.y);
    float q4 = bf_lo(qu.z), q5 = bf_hi(qu.z);
    float q6 = bf_lo(qu.w), q7 = bf_hi(qu.w);
    int e0 = offs[n], e1 = offs[n + 1];
    float m = -3.0e38f, z = 0.f;
    float a8[8] = {0.f, 0.f, 0.f, 0.f, 0.f, 0.f, 0.f, 0.f};
    for (int e = e0 + 2 * g; e < e1; e += 16) {
        int s0 = csr_src[e];
        bool has2 = (e + 1 < e1);
        int s1 = has2 ? csr_src[e + 1] : s0;
        const u16* kp0 = kv + (size_t)s0 * 128 + lg * 16;
        const u16* kp1 = kv + (size_t)s1 * 128 + lg * 16;
        uint4 ku0 = *(const uint4*)kp0;
        uint4 vu0 = *(const uint4*)(kp0 + 8);
        uint4 ku1 = *(const uint4*)kp1;
        uint4 vu1 = *(const uint4*)(kp1 + 8);
        float d0 = bf_lo(ku0.x) * q0;
        d0 = fmaf(bf_hi(ku0.x), q1, d0);
        d0 = fmaf(bf_lo(ku0.y), q2, d0);
        d0 = fmaf(bf_hi(ku0.y), q3, d0);
        d0 = fmaf(bf_lo(ku0.z), q4, d0);
        d0 = fmaf(bf_hi(ku0.z), q5, d0);
        d0 = fmaf(bf_lo(ku0.w), q6, d0);
        d0 = fmaf(bf_hi(ku0.w), q7, d0);
        float d1 = bf_lo(ku1.x) * q0;
        d1 = fmaf(bf_hi(ku1.x), q1, d1);
        d1 = fmaf(bf_lo(ku1.y), q2, d1);
        d1 = fmaf(bf_hi(ku1.y), q3, d1);
        d1 = fmaf(bf_lo(ku1.z), q4, d1);
        d1 = fmaf(bf_hi(ku1.z), q5, d1);
        d1 = fmaf(bf_lo(ku1.w), q6, d1);
        d1 = fmaf(bf_hi(ku1.w), q7, d1);
        d0 += __shfl_xor(d0, 1);
        d1 += __shfl_xor(d1, 1);
        d0 += __shfl_xor(d0, 2);
        d1 += __shfl_xor(d1, 2);
        d0 += __shfl_xor(d0, 4);
        d1 += __shfl_xor(d1, 4);
        float A0 = d0 * 0.125f;
        float A1 = has2 ? d1 * 0.125f : -3.0e38f;
        float mx = fmaxf(A0, A1);
        float diff = mx - m;
        if (__builtin_expect(diff > 25.f, 0)) {
            float c = __expf(-diff);
            z *= c;
            #pragma unroll
            for (int j = 0; j < 8; ++j) a8[j] *= c;
            m = mx;
        }
        float p0 = __expf(A0 - m);
        float p1 = has2 ? __expf(A1 - m) : 0.f;
        z += p0 + p1;
        a8[0] = fmaf(p0, bf_lo(vu0.x), fmaf(p1, bf_lo(vu1.x), a8[0]));
        a8[1] = fmaf(p0, bf_hi(vu0.x), fmaf(p1, bf_hi(vu1.x), a8[1]));
        a8[2] = fmaf(p0, bf_lo(vu0.y), fmaf(p1, bf_lo(vu1.y), a8[2]));
        a8[3] = fmaf(p0, bf_hi(vu0.y), fmaf(p1, bf_hi(vu1.y), a8[3]));
        a8[4] = fmaf(p0, bf_lo(vu0.z), fmaf(p1, bf_lo(vu1.z), a8[4]));
        a8[5] = fmaf(p0, bf_hi(vu0.z), fmaf(p1, bf_hi(vu1.z), a8[5]));
        a8[6] = fmaf(p0, bf_lo(vu0.w), fmaf(p1, bf_lo(vu1.w), a8[6]));
        a8[7] = fmaf(p0, bf_hi(vu0.w), fmaf(p1, bf_hi(vu1.w), a8[7]));
    }
    // combine 8 groups
    float M = m;
    M = fmaxf(M, __shfl_xor(M, 8));
    M = fmaxf(M, __shfl_xor(M, 16));
    M = fmaxf(M, __shfl_xor(M, 32));
    float s = __expf(m - M);
    z *= s;
    z += __shfl_xor(z, 8); z += __shfl_xor(z, 16); z += __shfl_xor(z, 32);
    #pragma unroll
    for (int j = 0; j < 8; ++j) {
        float a = a8[j] * s;
        a += __shfl_xor(a, 8); a += __shfl_xor(a, 16); a += __shfl_xor(a, 32);
        a8[j] = a;
    }
    if (g == 0) {
        float invz = 1.f / (z + 1e-16f);
        uint4 su = *(const uint4*)(sb16 + (size_t)n * 64 + lg * 8);
        float r0 = bf_lo(su.x) + a8[0] * invz;
        float r1 = bf_hi(su.x) + a8[1] * invz;
        float r2 = bf_lo(su.y) + a8[2] * invz;
        float r3 = bf_hi(su.y) + a8[3] * invz;
        float r4 = bf_lo(su.z) + a8[4] * invz;
        float r5 = bf_hi(su.z) + a8[5] * invz;
        float r6 = bf_lo(su.w) + a8[6] * invz;
        float r7 = bf_hi(su.w) + a8[7] * invz;
        if (last) {
            float* hp = hfin + (size_t)n * 64 + lg * 8;
            *(float4*)hp = make_float4(r0, r1, r2, r3);
            *(float4*)(hp + 4) = make_float4(r4, r5, r6, r7);
        } else {
            uint4 pk;
            pk.x = (u32)f2bf(r0) | ((u32)f2bf(r1) << 16);
            pk.y = (u32)f2bf(r2) | ((u32)f2bf(r3) << 16);
            pk.z = (u32)f2bf(r4) | ((u32)f2bf(r5) << 16);
            pk.w = (u32)f2bf(r6) | ((u32)f2bf(r7) << 16);
            *(uint4*)(hb + (size_t)n * 64 + lg * 8) = pk;
        }
    }
}

// ---------------- pooling ----------------
__global__ __launch_bounds__(256) void pool_sums(const float* __restrict__ h,
                                                 const int* __restrict__ batch,
                                                 float* __restrict__ gsums) {
    int b = blockIdx.x, t = threadIdx.x;
    int d = t & 63, sub = t >> 6;
    int lo = b * POOL_CHUNK;
    int hi = lo + POOL_CHUNK;
    if (hi > N_NODES) hi = N_NODES;
    float acc = 0.f;
    int curg = -1;
    for (int n = lo + sub; n < hi; n += 4) {
        int g = batch[n];
        if (g != curg) {
            if (curg >= 0) atomicAdd(&gsums[curg * 64 + d], acc);
            acc = 0.f;
            curg = g;
        }
        acc += h[(size_t)n * 64 + d];
    }
    if (curg >= 0) atomicAdd(&gsums[curg * 64 + d], acc);
}

__device__ __forceinline__ int lbound(const int* a, int n, int key) {
    int lo = 0, hi = n;
    while (lo < hi) {
        int mid = (lo + hi) >> 1;
        if (a[mid] < key) lo = mid + 1; else hi = mid;
    }
    return lo;
}

__global__ __launch_bounds__(256) void finalize(const float* __restrict__ gsums,
                                                const int* __restrict__ batch,
                                                const float* __restrict__ Wf,
                                                const float* __restrict__ bf,
                                                float* __restrict__ out) {
    __shared__ float pl[N_GRAPHS][DIM];
    __shared__ int bnd[N_GRAPHS + 1];
    int t = threadIdx.x;
    if (t <= N_GRAPHS) bnd[t] = (t == N_GRAPHS) ? N_NODES : lbound(batch, N_NODES, t);
    __syncthreads();
    for (int i = t; i < N_GRAPHS * DIM; i += 256) {
        int g = i >> 6;
        int cnt = bnd[g + 1] - bnd[g];
        pl[g][i & 63] = gsums[i] / (float)(cnt > 1 ? cnt : 1);
    }
    __syncthreads();
    for (int i = t; i < N_GRAPHS * OUT_DIM; i += 256) {
        int g = i / OUT_DIM, o = i % OUT_DIM;
        float acc = bf[o];
        #pragma unroll
        for (int d = 0; d < DIM; ++d) acc = fmaf(pl[g][d], Wf[d * OUT_DIM + o], acc);
        out[i] = acc;
    }
}

// ---------------- launch ----------------
extern "C" void kernel_launch(void* const* d_in, const int* in_sizes, int n_in,
                              void* d_out, int out_size, void* d_ws, size_t ws_size,
                              hipStream_t stream) {
    const float* x    = (const float*)d_in[0];
    const int*   ei   = (const int*)d_in[1];
    const int*   batch= (const int*)d_in[2];
    const float* Wq   = (const float*)d_in[3];
    const float* bq   = (const float*)d_in[4];
    const float* Wk   = (const float*)d_in[5];
    const float* bk   = (const float*)d_in[6];
    const float* Wv   = (const float*)d_in[7];
    const float* bv   = (const float*)d_in[8];
    const float* Ws   = (const float*)d_in[9];
    const float* bs   = (const float*)d_in[10];
    const float* Wf   = (const float*)d_in[11];
    const float* bf   = (const float*)d_in[12];
    float* out = (float*)d_out;

    char* ws = (char*)d_ws;
    u16*   qb16 = (u16*)  (ws + 0);            //  6.4 MB
    u16*   kvb  = (u16*)  (ws + 6400000);      // 12.8 MB interleaved k|v
    u16*   hb   = (u16*)  (ws + 19200000);     //  6.4 MB + 8 KB OOB-frag slack
    u16*   sb16 = (u16*)  (ws + 25608192);     //  6.4 MB (s-path bf16)
    float* hfin = (float*)(ws + 32008192);     // 12.8 MB (final layer f32)
    u16*   Wtb  = (u16*)  (ws + 44808192);     //  256 KB
    int*   csr  = (int*)  (ws + 45070336);     //  3.2 MB
    int*   offs = (int*)  (ws + 48270336);     //  200 KB
    u32*   bscr = (u32*)  (ws + 48470528);     //  3.92 MB
    int*   bcur = (int*)  (ws + 52390528);     //  784 B
    float* gsums= (float*)(ws + 52391424);     //  16 KB

    const int* srcI = ei;
    const int* dstI = ei + N_EDGES;

    // prep_w zeroes gsums + bcur in its tail -> no memset dispatch
    prep_w<<<49, 256, 0, stream>>>(Wq, Wk, Wv, Ws, Wtb, gsums, bcur);
    convert_x<<<(N_NODES * 8 + 255) / 256, 256, 0, stream>>>(x, hb);

    bucket_scatter<<<NBLK_A, 256, 0, stream>>>(srcI, dstI, bcur, bscr);
    csr_build<<<NBUCK, 256, 0, stream>>>(bscr, bcur, offs, csr);

    for (int l = 0; l < 4; ++l) {
        gemm_mfma<<<(N_NODES + 63) / 64, 256, 0, stream>>>(
            hb, Wtb + (size_t)l * 16384,
            bq + l * 64, bk + l * 64, bv + l * 64, bs + l * 64,
            qb16, kvb, sb16);
        edge_attn<<<N_NODES / 4, 256, 0, stream>>>(
            qb16, kvb, offs, csr, sb16, hfin, hb, (l == 3) ? 1 : 0);
    }
    pool_sums<<<POOL_BLOCKS, 256, 0, stream>>>(hfin, batch, gsums);
    finalize<<<1, 256, 0, stream>>>(gsums, batch, Wf, bf, out);
}

// Round 8
// 263.950 us; speedup vs baseline: 1.0749x; 1.0749x over previous
//
#include <hip/hip_runtime.h>
#include <hip/hip_bf16.h>

typedef unsigned short u16;
typedef unsigned int   u32;
typedef short bf16x8 __attribute__((ext_vector_type(8)));
typedef float f32x4  __attribute__((ext_vector_type(4)));

#define N_NODES  50000
#define N_EDGES  800000
#define DIM      64
#define N_GRAPHS 64
#define OUT_DIM  10
#define POOL_BLOCKS 256
#define POOL_CHUNK  ((N_NODES + POOL_BLOCKS - 1) / POOL_BLOCKS)   // 196

// bucket CSR build
#define BSHIFT 8
#define NBUCK  196
#define BCAP   5000
#define EPB    2048
#define NBLK_A ((N_EDGES + EPB - 1) / EPB)   // 391

__device__ __forceinline__ u16 f2bf(float f) {
    u32 u = __float_as_uint(f);
    u32 r = (u + 0x7fffu + ((u >> 16) & 1u)) >> 16;
    return (u16)r;
}
__device__ __forceinline__ float bf_lo(u32 u) { return __uint_as_float(u << 16); }
__device__ __forceinline__ float bf_hi(u32 u) { return __uint_as_float(u & 0xffff0000u); }

// ---------------- bucketed CSR build ----------------
__global__ __launch_bounds__(256) void bucket_scatter(const int* __restrict__ src,
                                                      const int* __restrict__ dst,
                                                      int* __restrict__ bcur,
                                                      u32* __restrict__ bscratch) {
    __shared__ int hist[NBUCK];
    __shared__ int base[NBUCK];
    int t = threadIdx.x;
    for (int i = t; i < NBUCK; i += 256) hist[i] = 0;
    __syncthreads();
    int e0 = blockIdx.x * EPB;
    u32 packed[8];
    int bb[8];
    #pragma unroll
    for (int i = 0; i < 8; ++i) {
        int e = e0 + i * 256 + t;
        if (e < N_EDGES) {
            int d = dst[e], s = src[e];
            bb[i] = d >> BSHIFT;
            packed[i] = ((u32)s << BSHIFT) | (u32)(d & ((1 << BSHIFT) - 1));
            atomicAdd(&hist[bb[i]], 1);
        } else bb[i] = -1;
    }
    __syncthreads();
    for (int i = t; i < NBUCK; i += 256)
        base[i] = (hist[i] > 0) ? atomicAdd(&bcur[i], hist[i]) : 0;
    __syncthreads();
    #pragma unroll
    for (int i = 0; i < 8; ++i) {
        if (bb[i] >= 0) {
            int pos = atomicAdd(&base[bb[i]], 1);
            bscratch[bb[i] * BCAP + pos] = packed[i];
        }
    }
}

__global__ __launch_bounds__(256) void csr_build(const u32* __restrict__ bscratch,
                                                 const int* __restrict__ bcur,
                                                 int* __restrict__ offs,
                                                 int* __restrict__ csr) {
    __shared__ int cnt[256];
    __shared__ int sc[256];
    __shared__ int cur2[256];
    __shared__ int gb[256];
    int b = blockIdx.x, t = threadIdx.x;
    int vb = (t < b) ? bcur[t] : 0;
    gb[t] = vb;
    cnt[t] = 0;
    __syncthreads();
    for (int d = 1; d < 256; d <<= 1) {
        int tmp = (t >= d) ? gb[t - d] : 0;
        __syncthreads();
        gb[t] += tmp;
        __syncthreads();
    }
    int gbase = gb[255];
    int n_b = bcur[b];
    const u32* bp = bscratch + (size_t)b * BCAP;
    for (int i = t; i < n_b; i += 256) atomicAdd(&cnt[bp[i] & 255], 1);
    __syncthreads();
    int v = cnt[t];
    sc[t] = v;
    __syncthreads();
    for (int d = 1; d < 256; d <<= 1) {
        int tmp = (t >= d) ? sc[t - d] : 0;
        __syncthreads();
        sc[t] += tmp;
        __syncthreads();
    }
    int excl = sc[t] - v;
    int node = (b << BSHIFT) + t;
    if (node < N_NODES) offs[node] = gbase + excl;
    if (b == NBUCK - 1 && t == 0) offs[N_NODES] = N_EDGES;
    cur2[t] = gbase + excl;
    __syncthreads();
    for (int i = t; i < n_b; i += 256) {
        u32 p = bp[i];
        int pos = atomicAdd(&cur2[p & 255], 1);
        csr[pos] = (int)(p >> BSHIFT);
    }
}

// ---------------- precompute ----------------

__global__ __launch_bounds__(256) void convert_x(const float* __restrict__ x,
                                                 u16* __restrict__ hb) {
    int c = blockIdx.x * 256 + threadIdx.x;
    if (c >= N_NODES * 8) return;
    const float* src = x + (size_t)c * 8;
    float4 f0 = *(const float4*)src;
    float4 f1 = *(const float4*)(src + 4);
    uint4 pk;
    pk.x = (u32)f2bf(f0.x) | ((u32)f2bf(f0.y) << 16);
    pk.y = (u32)f2bf(f0.z) | ((u32)f2bf(f0.w) << 16);
    pk.z = (u32)f2bf(f1.x) | ((u32)f2bf(f1.y) << 16);
    pk.w = (u32)f2bf(f1.z) | ((u32)f2bf(f1.w) << 16);
    *(uint4*)(hb + (size_t)c * 8) = pk;
}

// Mt[l][col][k] = sum_c Wq[l][k][c]*Wk[l][col][c]  (bf16)   [ids 0..2048)
// WvT[l][col][k] = Wv[l][k][col]                    (bf16)   [ids 2048..4096)
// WsT[l][col][k] = Ws[l][k][col]                    (bf16)   [ids 4096..6144)
// u[l][k] = sum_c bq[l][c]*Wk[l][k][c]              (f32)    [ids 6144..6400)
// gsums zero [6400..10496), bcur zero [10496..10692)
__global__ __launch_bounds__(256) void prep_mats(
    const float* __restrict__ Wq, const float* __restrict__ Wk,
    const float* __restrict__ Wv, const float* __restrict__ Ws,
    const float* __restrict__ bq,
    u16* __restrict__ Mtb, u16* __restrict__ WvTb, u16* __restrict__ WsTb,
    float* __restrict__ ubuf, float* __restrict__ gsums, int* __restrict__ bcur) {
    int id = blockIdx.x * 256 + threadIdx.x;
    if (id < 2048) {
        int kc = id & 7, col = (id >> 3) & 63, l = id >> 9;
        const float* wq = Wq + l * 4096;
        const float* wk = Wk + l * 4096 + col * 64;
        u16 b[8];
        #pragma unroll
        for (int j = 0; j < 8; ++j) {
            float acc = 0.f;
            const float* wqr = wq + (kc * 8 + j) * 64;
            for (int c = 0; c < 64; ++c) acc = fmaf(wqr[c], wk[c], acc);
            b[j] = f2bf(acc);
        }
        uint4 pk;
        pk.x = (u32)b[0] | ((u32)b[1] << 16);
        pk.y = (u32)b[2] | ((u32)b[3] << 16);
        pk.z = (u32)b[4] | ((u32)b[5] << 16);
        pk.w = (u32)b[6] | ((u32)b[7] << 16);
        *(uint4*)(Mtb + ((size_t)(l * 64 + col)) * 64 + kc * 8) = pk;
    } else if (id < 6144) {
        int i2 = id & 2047;
        int kc = i2 & 7, col = (i2 >> 3) & 63, l = i2 >> 9;
        const float* W = ((id < 4096) ? Wv : Ws) + l * 4096;
        u16* out = (id < 4096) ? WvTb : WsTb;
        u16 b[8];
        #pragma unroll
        for (int j = 0; j < 8; ++j) b[j] = f2bf(W[(kc * 8 + j) * 64 + col]);
        uint4 pk;
        pk.x = (u32)b[0] | ((u32)b[1] << 16);
        pk.y = (u32)b[2] | ((u32)b[3] << 16);
        pk.z = (u32)b[4] | ((u32)b[5] << 16);
        pk.w = (u32)b[6] | ((u32)b[7] << 16);
        *(uint4*)(out + ((size_t)(l * 64 + col)) * 64 + kc * 8) = pk;
    } else if (id < 6400) {
        int i2 = id - 6144;
        int k = i2 & 63, l = i2 >> 6;
        const float* bqr = bq + l * 64;
        const float* wkr = Wk + l * 4096 + k * 64;
        float acc = 0.f;
        for (int c = 0; c < 64; ++c) acc = fmaf(bqr[c], wkr[c], acc);
        ubuf[l * 64 + k] = acc;
    } else if (id < 6400 + N_GRAPHS * DIM) {
        gsums[id - 6400] = 0.f;
    } else if (id < 6400 + N_GRAPHS * DIM + NBUCK) {
        bcur[id - 6400 - N_GRAPHS * DIM] = 0;
    }
}

// ---------------- gemm_init: qt0 = x@M0 + u0, sb0 = x@Ws0 + bs0 (both bf16) ----------------
__global__ __launch_bounds__(256) void gemm_init(
    const u16* __restrict__ hb, const u16* __restrict__ Mtb, const u16* __restrict__ WsTb,
    const float* __restrict__ ubuf, const float* __restrict__ bs,
    u16* __restrict__ qt, u16* __restrict__ sb) {
    int t = threadIdx.x;
    int wave = t >> 6, lane = t & 63;
    int nb = blockIdx.x * 64;
    int lr = lane & 15, lg4 = lane >> 4;
    int mat = wave >> 1, c0 = (wave & 1) * 2;

    const u16* bbase = (mat == 0) ? Mtb : WsTb;
    const float* bias = (mat == 0) ? ubuf : bs;

    f32x4 acc[4][2];
    #pragma unroll
    for (int c2 = 0; c2 < 2; ++c2) {
        float bval = bias[(c0 + c2) * 16 + lr];
        #pragma unroll
        for (int rt = 0; rt < 4; ++rt) acc[rt][c2] = (f32x4){bval, bval, bval, bval};
    }
    #pragma unroll
    for (int s = 0; s < 2; ++s) {
        bf16x8 af[4], bfr[2];
        #pragma unroll
        for (int rt = 0; rt < 4; ++rt) {
            int node = nb + rt * 16 + lr;
            if (node >= N_NODES) node = 0;
            af[rt] = *(const bf16x8*)(hb + (size_t)node * 64 + s * 32 + lg4 * 8);
        }
        #pragma unroll
        for (int c2 = 0; c2 < 2; ++c2)
            bfr[c2] = *(const bf16x8*)(bbase + (size_t)((c0 + c2) * 16 + lr) * 64 + s * 32 + lg4 * 8);
        #pragma unroll
        for (int rt = 0; rt < 4; ++rt)
            #pragma unroll
            for (int c2 = 0; c2 < 2; ++c2)
                acc[rt][c2] = __builtin_amdgcn_mfma_f32_16x16x32_bf16(
                    af[rt], bfr[c2], acc[rt][c2], 0, 0, 0);
    }
    u16* out = (mat == 0) ? qt : sb;
    #pragma unroll
    for (int rt = 0; rt < 4; ++rt) {
        #pragma unroll
        for (int r = 0; r < 4; ++r) {
            int node = nb + rt * 16 + lg4 * 4 + r;
            if (node >= N_NODES) continue;
            #pragma unroll
            for (int c2 = 0; c2 < 2; ++c2)
                out[(size_t)node * 64 + (c0 + c2) * 16 + lr] = f2bf(acc[rt][c2][r]);
        }
    }
}

// ---------------- edge attention: gather h only (128B/edge), emit t = sum w*h ----------------
__global__ __launch_bounds__(256) void edge_attn(
    const u16* __restrict__ qt, const u16* __restrict__ hb,
    const int* __restrict__ offs, const int* __restrict__ csr_src,
    u16* __restrict__ tb, float* __restrict__ tz) {
    int wave = threadIdx.x >> 6, lane = threadIdx.x & 63;
    int n = blockIdx.x * 4 + wave;
    int g = lane >> 3, lg = lane & 7;
    uint4 qu = *(const uint4*)(qt + (size_t)n * 64 + lg * 8);
    float q0 = bf_lo(qu.x), q1 = bf_hi(qu.x);
    float q2 = bf_lo(qu.y), q3 = bf_hi(qu.y);
    float q4 = bf_lo(qu.z), q5 = bf_hi(qu.z);
    float q6 = bf_lo(qu.w), q7 = bf_hi(qu.w);
    int e0 = offs[n], e1 = offs[n + 1];
    float m = -3.0e38f, z = 0.f;
    float a8[8] = {0.f, 0.f, 0.f, 0.f, 0.f, 0.f, 0.f, 0.f};
    for (int e = e0 + 2 * g; e < e1; e += 16) {
        int s0 = csr_src[e];
        bool has2 = (e + 1 < e1);
        int s1 = has2 ? csr_src[e + 1] : s0;
        uint4 hu0 = *(const uint4*)(hb + (size_t)s0 * 64 + lg * 8);
        uint4 hu1 = *(const uint4*)(hb + (size_t)s1 * 64 + lg * 8);
        float h00 = bf_lo(hu0.x), h01 = bf_hi(hu0.x);
        float h02 = bf_lo(hu0.y), h03 = bf_hi(hu0.y);
        float h04 = bf_lo(hu0.z), h05 = bf_hi(hu0.z);
        float h06 = bf_lo(hu0.w), h07 = bf_hi(hu0.w);
        float h10 = bf_lo(hu1.x), h11 = bf_hi(hu1.x);
        float h12 = bf_lo(hu1.y), h13 = bf_hi(hu1.y);
        float h14 = bf_lo(hu1.z), h15 = bf_hi(hu1.z);
        float h16 = bf_lo(hu1.w), h17 = bf_hi(hu1.w);
        float d0 = h00 * q0;
        d0 = fmaf(h01, q1, d0); d0 = fmaf(h02, q2, d0); d0 = fmaf(h03, q3, d0);
        d0 = fmaf(h04, q4, d0); d0 = fmaf(h05, q5, d0); d0 = fmaf(h06, q6, d0);
        d0 = fmaf(h07, q7, d0);
        float d1 = h10 * q0;
        d1 = fmaf(h11, q1, d1); d1 = fmaf(h12, q2, d1); d1 = fmaf(h13, q3, d1);
        d1 = fmaf(h14, q4, d1); d1 = fmaf(h15, q5, d1); d1 = fmaf(h16, q6, d1);
        d1 = fmaf(h17, q7, d1);
        d0 += __shfl_xor(d0, 1);
        d1 += __shfl_xor(d1, 1);
        d0 += __shfl_xor(d0, 2);
        d1 += __shfl_xor(d1, 2);
        d0 += __shfl_xor(d0, 4);
        d1 += __shfl_xor(d1, 4);
        float A0 = d0 * 0.125f;
        float A1 = has2 ? d1 * 0.125f : -3.0e38f;
        float mx = fmaxf(A0, A1);
        float diff = mx - m;
        if (__builtin_expect(diff > 25.f, 0)) {
            float c = __expf(-diff);
            z *= c;
            #pragma unroll
            for (int j = 0; j < 8; ++j) a8[j] *= c;
            m = mx;
        }
        float p0 = __expf(A0 - m);
        float p1 = has2 ? __expf(A1 - m) : 0.f;
        z += p0 + p1;
        a8[0] = fmaf(p0, h00, fmaf(p1, h10, a8[0]));
        a8[1] = fmaf(p0, h01, fmaf(p1, h11, a8[1]));
        a8[2] = fmaf(p0, h02, fmaf(p1, h12, a8[2]));
        a8[3] = fmaf(p0, h03, fmaf(p1, h13, a8[3]));
        a8[4] = fmaf(p0, h04, fmaf(p1, h14, a8[4]));
        a8[5] = fmaf(p0, h05, fmaf(p1, h15, a8[5]));
        a8[6] = fmaf(p0, h06, fmaf(p1, h16, a8[6]));
        a8[7] = fmaf(p0, h07, fmaf(p1, h17, a8[7]));
    }
    float M = m;
    M = fmaxf(M, __shfl_xor(M, 8));
    M = fmaxf(M, __shfl_xor(M, 16));
    M = fmaxf(M, __shfl_xor(M, 32));
    float s = __expf(m - M);
    z *= s;
    z += __shfl_xor(z, 8); z += __shfl_xor(z, 16); z += __shfl_xor(z, 32);
    #pragma unroll
    for (int j = 0; j < 8; ++j) {
        float a = a8[j] * s;
        a += __shfl_xor(a, 8); a += __shfl_xor(a, 16); a += __shfl_xor(a, 32);
        a8[j] = a;
    }
    if (g == 0) {
        float invz = 1.f / (z + 1e-16f);
        uint4 pk;
        pk.x = (u32)f2bf(a8[0] * invz) | ((u32)f2bf(a8[1] * invz) << 16);
        pk.y = (u32)f2bf(a8[2] * invz) | ((u32)f2bf(a8[3] * invz) << 16);
        pk.z = (u32)f2bf(a8[4] * invz) | ((u32)f2bf(a8[5] * invz) << 16);
        pk.w = (u32)f2bf(a8[6] * invz) | ((u32)f2bf(a8[7] * invz) << 16);
        *(uint4*)(tb + (size_t)n * 64 + lg * 8) = pk;
        if (lg == 0) tz[n] = (e1 > e0) ? 1.f : 0.f;
    }
}

// ---------------- gemm_layer: h_next = t@Wv + tz*bv + sb ; then qt_next, sb_next ----------------
__global__ __launch_bounds__(256) void gemm_layer(
    const u16* __restrict__ tb, u16* __restrict__ sb, const float* __restrict__ tz,
    const u16* __restrict__ WvT, const float* __restrict__ bv,
    const u16* __restrict__ Mtn, const float* __restrict__ un,
    const u16* __restrict__ WsTn, const float* __restrict__ bsn,
    u16* __restrict__ hb, u16* __restrict__ qt) {
    __shared__ float ldsF[64 * 67];   // 17152 B
    __shared__ u16  ldsA[64 * 72];    //  9216 B
    int t = threadIdx.x;
    int wave = t >> 6, lane = t & 63;
    int nb = blockIdx.x * 64;
    int lr = lane & 15, lg4 = lane >> 4;

    // phase 1: t @ WvT, wave w -> cols w*16..w*16+15
    f32x4 acc1[4];
    #pragma unroll
    for (int rt = 0; rt < 4; ++rt) acc1[rt] = (f32x4){0.f, 0.f, 0.f, 0.f};
    #pragma unroll
    for (int s = 0; s < 2; ++s) {
        bf16x8 af[4], bfr;
        #pragma unroll
        for (int rt = 0; rt < 4; ++rt) {
            int node = nb + rt * 16 + lr;
            if (node >= N_NODES) node = 0;
            af[rt] = *(const bf16x8*)(tb + (size_t)node * 64 + s * 32 + lg4 * 8);
        }
        bfr = *(const bf16x8*)(WvT + (size_t)(wave * 16 + lr) * 64 + s * 32 + lg4 * 8);
        #pragma unroll
        for (int rt = 0; rt < 4; ++rt)
            acc1[rt] = __builtin_amdgcn_mfma_f32_16x16x32_bf16(af[rt], bfr, acc1[rt], 0, 0, 0);
    }
    // phase 2: stash to LDS f32 (row, col)
    #pragma unroll
    for (int rt = 0; rt < 4; ++rt)
        #pragma unroll
        for (int r = 0; r < 4; ++r)
            ldsF[(rt * 16 + lg4 * 4 + r) * 67 + wave * 16 + lr] = acc1[rt][r];
    __syncthreads();
    // phase 3: h_next = ldsF + tz*bv + sb -> hb (bf16) + ldsA
    {
        int row = t >> 2, cg = (t & 3) * 16;
        int node = nb + row;
        int rnode = (node < N_NODES) ? node : 0;
        const u16* sp = sb + (size_t)rnode * 64 + cg;
        uint4 s0 = *(const uint4*)sp;
        uint4 s1 = *(const uint4*)(sp + 8);
        float tzv = tz[rnode];
        float vals[16];
        float sv[16] = {
            bf_lo(s0.x), bf_hi(s0.x), bf_lo(s0.y), bf_hi(s0.y),
            bf_lo(s0.z), bf_hi(s0.z), bf_lo(s0.w), bf_hi(s0.w),
            bf_lo(s1.x), bf_hi(s1.x), bf_lo(s1.y), bf_hi(s1.y),
            bf_lo(s1.z), bf_hi(s1.z), bf_lo(s1.w), bf_hi(s1.w)};
        #pragma unroll
        for (int j = 0; j < 16; ++j)
            vals[j] = ldsF[row * 67 + cg + j] + tzv * bv[cg + j] + sv[j];
        uint4 pk0, pk1;
        u16 hb16[16];
        #pragma unroll
        for (int j = 0; j < 16; ++j) hb16[j] = f2bf(vals[j]);
        pk0.x = (u32)hb16[0] | ((u32)hb16[1] << 16);
        pk0.y = (u32)hb16[2] | ((u32)hb16[3] << 16);
        pk0.z = (u32)hb16[4] | ((u32)hb16[5] << 16);
        pk0.w = (u32)hb16[6] | ((u32)hb16[7] << 16);
        pk1.x = (u32)hb16[8] | ((u32)hb16[9] << 16);
        pk1.y = (u32)hb16[10] | ((u32)hb16[11] << 16);
        pk1.z = (u32)hb16[12] | ((u32)hb16[13] << 16);
        pk1.w = (u32)hb16[14] | ((u32)hb16[15] << 16);
        if (node < N_NODES) {
            *(uint4*)(hb + (size_t)node * 64 + cg) = pk0;
            *(uint4*)(hb + (size_t)node * 64 + cg + 8) = pk1;
        }
        *(uint4*)(ldsA + row * 72 + cg) = pk0;
        *(uint4*)(ldsA + row * 72 + cg + 8) = pk1;
    }
    __syncthreads();
    // phase 4: qt_next (waves 0,1) / sb_next (waves 2,3) from ldsA
    int mat = wave >> 1, c0 = (wave & 1) * 2;
    const u16* bbase = (mat == 0) ? Mtn : WsTn;
    const float* bias = (mat == 0) ? un : bsn;
    f32x4 acc2[4][2];
    #pragma unroll
    for (int c2 = 0; c2 < 2; ++c2) {
        float bval = bias[(c0 + c2) * 16 + lr];
        #pragma unroll
        for (int rt = 0; rt < 4; ++rt) acc2[rt][c2] = (f32x4){bval, bval, bval, bval};
    }
    #pragma unroll
    for (int s = 0; s < 2; ++s) {
        bf16x8 af[4], bfr[2];
        #pragma unroll
        for (int rt = 0; rt < 4; ++rt)
            af[rt] = *(const bf16x8*)(ldsA + (rt * 16 + lr) * 72 + s * 32 + lg4 * 8);
        #pragma unroll
        for (int c2 = 0; c2 < 2; ++c2)
            bfr[c2] = *(const bf16x8*)(bbase + (size_t)((c0 + c2) * 16 + lr) * 64 + s * 32 + lg4 * 8);
        #pragma unroll
        for (int rt = 0; rt < 4; ++rt)
            #pragma unroll
            for (int c2 = 0; c2 < 2; ++c2)
                acc2[rt][c2] = __builtin_amdgcn_mfma_f32_16x16x32_bf16(
                    af[rt], bfr[c2], acc2[rt][c2], 0, 0, 0);
    }
    u16* outp = (mat == 0) ? qt : sb;
    #pragma unroll
    for (int rt = 0; rt < 4; ++rt) {
        #pragma unroll
        for (int r = 0; r < 4; ++r) {
            int node = nb + rt * 16 + lg4 * 4 + r;
            if (node >= N_NODES) continue;
            #pragma unroll
            for (int c2 = 0; c2 < 2; ++c2)
                outp[(size_t)node * 64 + (c0 + c2) * 16 + lr] = f2bf(acc2[rt][c2][r]);
        }
    }
}

// ---------------- gemm_final: hfin = t@Wv + tz*bv + sb (f32) ----------------
__global__ __launch_bounds__(256) void gemm_final(
    const u16* __restrict__ tb, const u16* __restrict__ sb, const float* __restrict__ tz,
    const u16* __restrict__ WvT, const float* __restrict__ bv,
    float* __restrict__ hfin) {
    __shared__ float ldsF[64 * 67];
    int t = threadIdx.x;
    int wave = t >> 6, lane = t & 63;
    int nb = blockIdx.x * 64;
    int lr = lane & 15, lg4 = lane >> 4;

    f32x4 acc1[4];
    #pragma unroll
    for (int rt = 0; rt < 4; ++rt) acc1[rt] = (f32x4){0.f, 0.f, 0.f, 0.f};
    #pragma unroll
    for (int s = 0; s < 2; ++s) {
        bf16x8 af[4], bfr;
        #pragma unroll
        for (int rt = 0; rt < 4; ++rt) {
            int node = nb + rt * 16 + lr;
            if (node >= N_NODES) node = 0;
            af[rt] = *(const bf16x8*)(tb + (size_t)node * 64 + s * 32 + lg4 * 8);
        }
        bfr = *(const bf16x8*)(WvT + (size_t)(wave * 16 + lr) * 64 + s * 32 + lg4 * 8);
        #pragma unroll
        for (int rt = 0; rt < 4; ++rt)
            acc1[rt] = __builtin_amdgcn_mfma_f32_16x16x32_bf16(af[rt], bfr, acc1[rt], 0, 0, 0);
    }
    #pragma unroll
    for (int rt = 0; rt < 4; ++rt)
        #pragma unroll
        for (int r = 0; r < 4; ++r)
            ldsF[(rt * 16 + lg4 * 4 + r) * 67 + wave * 16 + lr] = acc1[rt][r];
    __syncthreads();
    {
        int row = t >> 2, cg = (t & 3) * 16;
        int node = nb + row;
        if (node < N_NODES) {
            const u16* sp = sb + (size_t)node * 64 + cg;
            uint4 s0 = *(const uint4*)sp;
            uint4 s1 = *(const uint4*)(sp + 8);
            float sv[16] = {
                bf_lo(s0.x), bf_hi(s0.x), bf_lo(s0.y), bf_hi(s0.y),
                bf_lo(s0.z), bf_hi(s0.z), bf_lo(s0.w), bf_hi(s0.w),
                bf_lo(s1.x), bf_hi(s1.x), bf_lo(s1.y), bf_hi(s1.y),
                bf_lo(s1.z), bf_hi(s1.z), bf_lo(s1.w), bf_hi(s1.w)};
            float tzv = tz[node];
            float* op = hfin + (size_t)node * 64 + cg;
            #pragma unroll
            for (int j4 = 0; j4 < 4; ++j4) {
                float4 o;
                o.x = ldsF[row * 67 + cg + j4 * 4 + 0] + tzv * bv[cg + j4 * 4 + 0] + sv[j4 * 4 + 0];
                o.y = ldsF[row * 67 + cg + j4 * 4 + 1] + tzv * bv[cg + j4 * 4 + 1] + sv[j4 * 4 + 1];
                o.z = ldsF[row * 67 + cg + j4 * 4 + 2] + tzv * bv[cg + j4 * 4 + 2] + sv[j4 * 4 + 2];
                o.w = ldsF[row * 67 + cg + j4 * 4 + 3] + tzv * bv[cg + j4 * 4 + 3] + sv[j4 * 4 + 3];
                *(float4*)(op + j4 * 4) = o;
            }
        }
    }
}

// ---------------- pooling ----------------
__global__ __launch_bounds__(256) void pool_sums(const float* __restrict__ h,
                                                 const int* __restrict__ batch,
                                                 float* __restrict__ gsums) {
    int b = blockIdx.x, t = threadIdx.x;
    int d = t & 63, sub = t >> 6;
    int lo = b * POOL_CHUNK;
    int hi = lo + POOL_CHUNK;
    if (hi > N_NODES) hi = N_NODES;
    float acc = 0.f;
    int curg = -1;
    for (int n = lo + sub; n < hi; n += 4) {
        int g = batch[n];
        if (g != curg) {
            if (curg >= 0) atomicAdd(&gsums[curg * 64 + d], acc);
            acc = 0.f;
            curg = g;
        }
        acc += h[(size_t)n * 64 + d];
    }
    if (curg >= 0) atomicAdd(&gsums[curg * 64 + d], acc);
}

__device__ __forceinline__ int lbound(const int* a, int n, int key) {
    int lo = 0, hi = n;
    while (lo < hi) {
        int mid = (lo + hi) >> 1;
        if (a[mid] < key) lo = mid + 1; else hi = mid;
    }
    return lo;
}

__global__ __launch_bounds__(256) void finalize(const float* __restrict__ gsums,
                                                const int* __restrict__ batch,
                                                const float* __restrict__ Wf,
                                                const float* __restrict__ bf,
                                                float* __restrict__ out) {
    __shared__ float pl[N_GRAPHS][DIM];
    __shared__ int bnd[N_GRAPHS + 1];
    int t = threadIdx.x;
    if (t <= N_GRAPHS) bnd[t] = (t == N_GRAPHS) ? N_NODES : lbound(batch, N_NODES, t);
    __syncthreads();
    for (int i = t; i < N_GRAPHS * DIM; i += 256) {
        int g = i >> 6;
        int cnt = bnd[g + 1] - bnd[g];
        pl[g][i & 63] = gsums[i] / (float)(cnt > 1 ? cnt : 1);
    }
    __syncthreads();
    for (int i = t; i < N_GRAPHS * OUT_DIM; i += 256) {
        int g = i / OUT_DIM, o = i % OUT_DIM;
        float acc = bf[o];
        #pragma unroll
        for (int d = 0; d < DIM; ++d) acc = fmaf(pl[g][d], Wf[d * OUT_DIM + o], acc);
        out[i] = acc;
    }
}

// ---------------- launch ----------------
extern "C" void kernel_launch(void* const* d_in, const int* in_sizes, int n_in,
                              void* d_out, int out_size, void* d_ws, size_t ws_size,
                              hipStream_t stream) {
    const float* x    = (const float*)d_in[0];
    const int*   ei   = (const int*)d_in[1];
    const int*   batch= (const int*)d_in[2];
    const float* Wq   = (const float*)d_in[3];
    const float* bq   = (const float*)d_in[4];
    const float* Wk   = (const float*)d_in[5];
    const float* bk   = (const float*)d_in[6];
    const float* Wv   = (const float*)d_in[7];
    const float* bv   = (const float*)d_in[8];
    const float* Ws   = (const float*)d_in[9];
    const float* bs   = (const float*)d_in[10];
    const float* Wf   = (const float*)d_in[11];
    const float* bf   = (const float*)d_in[12];
    float* out = (float*)d_out;

    char* ws = (char*)d_ws;
    u16*   qtb  = (u16*)  (ws + 0);            //  6.4 MB
    u16*   hb   = (u16*)  (ws + 6400000);      //  6.4 MB (+slack)
    u16*   tb   = (u16*)  (ws + 12808192);     //  6.4 MB (+slack)
    u16*   sbb  = (u16*)  (ws + 19216384);     //  6.4 MB
    float* hfin = (float*)(ws + 25616384);     // 12.8 MB
    u16*   Mtb  = (u16*)  (ws + 38416384);     //  32 KB
    u16*   WvTb = (u16*)  (ws + 38449152);     //  32 KB
    u16*   WsTb = (u16*)  (ws + 38481920);     //  32 KB
    float* ubuf = (float*)(ws + 38514688);     //  1 KB
    int*   bcur = (int*)  (ws + 38515712);     //  1 KB
    int*   csr  = (int*)  (ws + 38516736);     //  3.2 MB
    int*   offs = (int*)  (ws + 41716736);     //  200 KB
    u32*   bscr = (u32*)  (ws + 41917440);     //  3.92 MB
    float* gsums= (float*)(ws + 45837440);     //  16 KB
    float* tz   = (float*)(ws + 45853824);     //  200 KB

    const int* srcI = ei;
    const int* dstI = ei + N_EDGES;

    prep_mats<<<42, 256, 0, stream>>>(Wq, Wk, Wv, Ws, bq, Mtb, WvTb, WsTb, ubuf, gsums, bcur);
    convert_x<<<(N_NODES * 8 + 255) / 256, 256, 0, stream>>>(x, hb);

    bucket_scatter<<<NBLK_A, 256, 0, stream>>>(srcI, dstI, bcur, bscr);
    csr_build<<<NBUCK, 256, 0, stream>>>(bscr, bcur, offs, csr);

    const int NB = (N_NODES + 63) / 64;
    gemm_init<<<NB, 256, 0, stream>>>(hb, Mtb, WsTb, ubuf, bs, qtb, sbb);

    for (int l = 0; l < 3; ++l) {
        edge_attn<<<N_NODES / 4, 256, 0, stream>>>(qtb, hb, offs, csr, tb, tz);
        gemm_layer<<<NB, 256, 0, stream>>>(
            tb, sbb, tz,
            WvTb + (size_t)l * 4096, bv + l * 64,
            Mtb + (size_t)(l + 1) * 4096, ubuf + (l + 1) * 64,
            WsTb + (size_t)(l + 1) * 4096, bs + (l + 1) * 64,
            hb, qtb);
    }
    edge_attn<<<N_NODES / 4, 256, 0, stream>>>(qtb, hb, offs, csr, tb, tz);
    gemm_final<<<NB, 256, 0, stream>>>(tb, sbb, tz, WvTb + 3 * 4096, bv + 3 * 64, hfin);

    pool_sums<<<POOL_BLOCKS, 256, 0, stream>>>(hfin, batch, gsums);
    finalize<<<1, 256, 0, stream>>>(gsums, batch, Wf, bf, out);
}